// Round 6
// baseline (529.137 us; speedup 1.0000x reference)
//
#include <hip/hip_runtime.h>

typedef __bf16 bf16;
typedef __bf16 bf16x8 __attribute__((ext_vector_type(8)));
typedef float f32x4 __attribute__((ext_vector_type(4)));
typedef float f32x16 __attribute__((ext_vector_type(16)));

// async global->LDS, 16B per lane; LDS dest is wave-uniform base + lane*16
__device__ __forceinline__ void gl_lds16(const bf16* g, bf16* l) {
  __builtin_amdgcn_global_load_lds(
      (__attribute__((address_space(1))) void*)g,
      (__attribute__((address_space(3))) void*)l, 16, 0, 0);
}

// ---------------- fp32 -> bf16 convert, 8 elems/thread ----------------
__global__ __launch_bounds__(256) void cvt_f32_bf16(
    const float* __restrict__ src, bf16* __restrict__ dst, int n8) {
  int i = blockIdx.x * 256 + threadIdx.x;
  if (i >= n8) return;
  const float4* s4 = (const float4*)src;
  float4 a = s4[2 * i], b = s4[2 * i + 1];
  bf16x8 o = {(bf16)a.x, (bf16)a.y, (bf16)a.z, (bf16)a.w,
              (bf16)b.x, (bf16)b.y, (bf16)b.z, (bf16)b.w};
  *(bf16x8*)(dst + (size_t)i * 8) = o;
}

// ------- V [2048,1024] f32 -> VT [1024,2048] bf16, per batch ----------
__global__ __launch_bounds__(256) void transpose_v(
    const float* __restrict__ V, bf16* __restrict__ VT) {
  int b = blockIdx.z;
  const float* Vb = V + (size_t)b * 2048 * 1024;
  bf16* Tb = VT + (size_t)b * 1024 * 2048;
  __shared__ float tile[32][33];  // +1 pad: conflict-free transposed read
  int tx = threadIdx.x, ty = threadIdx.y;
  int x = blockIdx.x * 32 + tx;
  int yb = blockIdx.y * 32;
#pragma unroll
  for (int j = 0; j < 4; j++)
    tile[ty + j * 8][tx] = Vb[(size_t)(yb + ty + j * 8) * 1024 + x];
  __syncthreads();
  int xo = yb + tx;
#pragma unroll
  for (int j = 0; j < 4; j++)
    Tb[(size_t)(blockIdx.x * 32 + ty + j * 8) * 2048 + xo] =
        (bf16)tile[tx][ty + j * 8];
}

// ========== 256x256 4-phase-per-tile pipelined MFMA GEMM (m201 shape) ==
// C = A[M,K] * Bm[N,K]^T, bf16 in, 32x32x16 MFMA.
// 512 thr = 8 waves, per-phase wave slice 64x32, acc[q][mi2] 4x2 f32x16.
// R5 post-mortem: 2-barrier-per-tile = m233 stall (period 6600cy vs 2065
//   MFMA floor; MfmaUtil == floor/period across R3-R5). Fix = m201 phase
//   schedule, not more in-tile reordering (m131-m141 null).
// Phase q of K-tile t (quadrant mh=q>>1, nh=q&1):
//   { 12 ds_read (2 mi2 x 4 kk A-frags + 4 kk B-frags)
//     stage ONE half-tile of t+1 (2 gl_lds; order A0,B0,B1,A1)
//     barrier; lgkmcnt(0)+sched_barrier; setprio(1); 8 MFMA; setprio(0);
//     vmcnt(4/4/6/4) counted guard for NEXT phase's reads; barrier }
// FIFO-derived guards (2 loads per half-tile): ph-q reads need
//   q0:{t.A0,t.B0} q1:{t.B1} q2:{t.A1} q3:{}; guard at end of q-1 leaves
//   newest 4 (or 6) outstanding => needed halves landed, >=2 halves always
//   in flight (never drains mid-loop). Prefetch distance 3-4 phases.
// Swizzle unchanged (R4): slot = g ^ (r&7) ^ (((r>>3)&3)<<1); conflict
//   counter is read-pattern floor (4cy/b128), not targeted.
// MODE 0: C bf16 = acc + bias[col]            (projection)
// MODE 1: C bf16 = mask[col] ? acc/32 : -1e9  (QK^T scores)
// MODE 2: C f32  = acc                        (PV output)
template <int MODE, int ZMAP>
__global__ __launch_bounds__(512, 2) void gemm256(
    const bf16* __restrict__ A, const bf16* __restrict__ Bm,
    void* __restrict__ Cv, const float* __restrict__ bias,
    const int* __restrict__ mask, int M, int N, int K,
    long long sA, long long sB, long long sC) {
  int b, m0, n0;
  if constexpr (ZMAP == 1) {
    // batch-partitioned: XCD c owns batch c entirely (R4: FETCH 148->49MB)
    const int L = (blockIdx.z * gridDim.y + blockIdx.y) * gridDim.x +
                  blockIdx.x;
    b = L & 7;
    const int J = L >> 3;  // tile within batch
    m0 = (J / gridDim.x) * 256;
    n0 = (J % gridDim.x) * 256;
  } else {
    // single-plane rect scheme (proven): per-XCD 8m x 4n block cluster
    b = blockIdx.z;
    const int nx = gridDim.x, nwg = nx * gridDim.y;
    const int orig = blockIdx.y * nx + blockIdx.x;
    const int swz = (orig & 7) * (nwg >> 3) + (orig >> 3);
    m0 = (swz / nx) * 256;
    n0 = (swz % nx) * 256;
  }
  const bf16* Ab = A + (long long)b * sA;
  const bf16* Bb = Bm + (long long)b * sB;

  __shared__ __align__(16) bf16 lds[2][2][256 * 64];  // [buf][A/B][r*64+k]

  const int tid = threadIdx.x, w = tid >> 6, lane = tid & 63;
  const int wr = w >> 2, wc = w & 3;  // wave grid 2x4
  const int fr = lane & 31;           // frag row within 32-tile
  const int fh = lane >> 5;           // k-granule half selector
  const int key = (fr & 7) ^ (((fr >> 3) & 3) << 1);  // read swizzle key
  const bf16* Aq = Ab + (long long)m0 * K;
  const bf16* Bq = Bb + (long long)n0 * K;

  f32x16 acc[4][2];  // [phase/quadrant][mi2]
#pragma unroll
  for (int i = 0; i < 4; i++)
#pragma unroll
    for (int j = 0; j < 2; j++)
#pragma unroll
      for (int r = 0; r < 16; r++) acc[i][j][r] = 0.f;

  // ---- stage one half-tile (128 rows) of matrix mat for K-tile t ----
  // 2 gl_lds/wave; wave w covers rows w*8+srow of each 64-row sub-block.
  const int srow = lane >> 3;
  const int sgsw = (((lane & 7) ^ srow ^ ((w & 3) << 1)) * 8);
  auto stage_half = [&](int t, int mat, int half) {
    const int buf = t & 1;
    const long long gc = (long long)t * 64 + sgsw;
    const bf16* src = mat ? Bq : Aq;
#pragma unroll
    for (int j = 0; j < 2; j++) {
      const long long r = half * 128 + j * 64 + w * 8 + srow;
      const int dbase = (half * 128 + j * 64 + w * 8) * 64;  // uniform
      gl_lds16(src + r * K + gc, &lds[buf][mat][dbase]);
    }
  };

  const int NT = K >> 6;  // BK=64 tiles (16 or 32 here)
  // prologue: stage tile 0's four halves in consumption order
  stage_half(0, 0, 0);  // A0
  stage_half(0, 1, 0);  // B0
  stage_half(0, 1, 1);  // B1
  stage_half(0, 0, 1);  // A1
  asm volatile("s_waitcnt vmcnt(4)" ::: "memory");  // A0,B0 landed
  __builtin_amdgcn_s_barrier();

  for (int t = 0; t < NT; ++t) {
    if (t == NT - 1) {  // final tile: drain once, no guards inside
      asm volatile("s_waitcnt vmcnt(0)" ::: "memory");
      __builtin_amdgcn_s_barrier();
    }
    const int buf = t & 1;
    const bf16* la = &lds[buf][0][0];
    const bf16* lb = &lds[buf][1][0];
#pragma unroll
    for (int q = 0; q < 4; q++) {
      const int mh = q >> 1, nh = q & 1;
      // 12 ds_reads for quadrant q (latency hides under barrier wait)
      bf16x8 afv[2][4], bfv[4];
#pragma unroll
      for (int kk = 0; kk < 4; kk++) {
        const int slot = ((kk * 2 + fh) ^ key) * 8;
#pragma unroll
        for (int mi2 = 0; mi2 < 2; mi2++)
          afv[mi2][kk] = *(const bf16x8*)&la
              [(mh * 128 + wr * 64 + mi2 * 32 + fr) * 64 + slot];
        bfv[kk] =
            *(const bf16x8*)&lb[(nh * 128 + wc * 32 + fr) * 64 + slot];
      }
      // stage one half-tile of t+1: order A0,B0,B1,A1
      if (t + 1 < NT) {
        constexpr int smat[4] = {0, 1, 1, 0};
        constexpr int shalf[4] = {0, 0, 1, 1};
        stage_half(t + 1, smat[q], shalf[q]);
      }
      __builtin_amdgcn_s_barrier();
      asm volatile("s_waitcnt lgkmcnt(0)" ::: "memory");
      __builtin_amdgcn_sched_barrier(0);  // rule #18: pin MFMA after wait
      __builtin_amdgcn_s_setprio(1);
#pragma unroll
      for (int kk = 0; kk < 4; kk++)
#pragma unroll
        for (int mi2 = 0; mi2 < 2; mi2++)
          acc[q][mi2] = __builtin_amdgcn_mfma_f32_32x32x16_bf16(
              afv[mi2][kk], bfv[kk], acc[q][mi2], 0, 0, 0);
      __builtin_amdgcn_s_setprio(0);
      // counted guard for next phase's reads (never drains mid-loop)
      if (t + 1 < NT) {
        if (q == 2)
          asm volatile("s_waitcnt vmcnt(6)" ::: "memory");
        else
          asm volatile("s_waitcnt vmcnt(4)" ::: "memory");
      }
      __builtin_amdgcn_s_barrier();
    }
  }

  // C/D layout (m74/m101-verified): col=lane&31,
  // row = (reg&3) + 8*(reg>>2) + 4*(lane>>5)
  const int ecol = lane & 31, er4 = (lane >> 5) * 4;
  if constexpr (MODE == 0) {
    bf16* C = (bf16*)Cv;
#pragma unroll
    for (int q = 0; q < 4; q++) {
      int col = n0 + (q & 1) * 128 + wc * 32 + ecol;
      float bv = bias[col];
#pragma unroll
      for (int mi2 = 0; mi2 < 2; mi2++)
#pragma unroll
        for (int r = 0; r < 16; r++) {
          int row = m0 + (q >> 1) * 128 + wr * 64 + mi2 * 32 + er4 +
                    (r & 3) + 8 * (r >> 2);
          C[(long long)row * N + col] = (bf16)(acc[q][mi2][r] + bv);
        }
    }
  } else if constexpr (MODE == 1) {
    bf16* C = (bf16*)Cv + (long long)b * sC;
    const int* mb = mask + b * 2048;
#pragma unroll
    for (int q = 0; q < 4; q++) {
      int col = n0 + (q & 1) * 128 + wc * 32 + ecol;
      bool keep = mb[col] != 0;
#pragma unroll
      for (int mi2 = 0; mi2 < 2; mi2++)
#pragma unroll
        for (int r = 0; r < 16; r++) {
          int row = m0 + (q >> 1) * 128 + wr * 64 + mi2 * 32 + er4 +
                    (r & 3) + 8 * (r >> 2);
          C[(long long)row * N + col] =
              keep ? (bf16)(acc[q][mi2][r] * 0.03125f) : (bf16)(-1e9f);
        }
    }
  } else {
    float* C = (float*)Cv + (long long)b * sC;
#pragma unroll
    for (int q = 0; q < 4; q++) {
      int col = n0 + (q & 1) * 128 + wc * 32 + ecol;
#pragma unroll
      for (int mi2 = 0; mi2 < 2; mi2++)
#pragma unroll
        for (int r = 0; r < 16; r++) {
          int row = m0 + (q >> 1) * 128 + wr * 64 + mi2 * 32 + er4 +
                    (r & 3) + 8 * (r >> 2);
          C[(long long)row * N + col] = acc[q][mi2][r];
        }
    }
  }
}

// ------------- row softmax: S bf16 [.,2048] -> P bf16 -----------------
__global__ __launch_bounds__(256) void softmax_rows(
    const bf16* __restrict__ S, bf16* __restrict__ P) {
  long long row = blockIdx.x;
  const bf16x8* src = (const bf16x8*)(S + row * 2048);
  int tid = threadIdx.x, w = tid >> 6, lane = tid & 63;
  bf16x8 v = src[tid];
  float f[8];
#pragma unroll
  for (int i = 0; i < 8; i++) f[i] = (float)v[i];
  float m = f[0];
#pragma unroll
  for (int i = 1; i < 8; i++) m = fmaxf(m, f[i]);
#pragma unroll
  for (int off = 32; off; off >>= 1) m = fmaxf(m, __shfl_xor(m, off, 64));
  __shared__ float redm[4], reds[4];
  if (lane == 0) redm[w] = m;
  __syncthreads();
  m = fmaxf(fmaxf(redm[0], redm[1]), fmaxf(redm[2], redm[3]));
  float e[8], s = 0.f;
#pragma unroll
  for (int i = 0; i < 8; i++) {
    e[i] = __expf(f[i] - m);
    s += e[i];
  }
#pragma unroll
  for (int off = 32; off; off >>= 1) s += __shfl_xor(s, off, 64);
  if (lane == 0) reds[w] = s;
  __syncthreads();
  s = reds[0] + reds[1] + reds[2] + reds[3];
  float inv = 1.0f / s;
  bf16x8 o;
#pragma unroll
  for (int i = 0; i < 8; i++) o[i] = (bf16)(e[i] * inv);
  *(bf16x8*)(P + row * 2048 + tid * 8) = o;
}

extern "C" void kernel_launch(void* const* d_in, const int* in_sizes, int n_in,
                              void* d_out, int out_size, void* d_ws,
                              size_t ws_size, hipStream_t stream) {
  const float* query = (const float*)d_in[0];
  const float* key_in = (const float*)d_in[1];
  const float* value = (const float*)d_in[2];
  const int* mask = (const int*)d_in[3];
  const float* Wq_w = (const float*)d_in[4];
  const float* Wq_b = (const float*)d_in[5];
  const float* Wk_w = (const float*)d_in[6];
  const float* Wk_b = (const float*)d_in[7];
  float* out = (float*)d_out;

  // workspace layout (224 MB), regions time-shared:
  //  [0,128MB):  qx(32) kx(32) wq(2) wk(2)  -> then S bf16 (64)
  //  [128,192MB): qp(32) kp(32)             -> then P bf16 (64)
  //  [192,224MB): vt bf16 (32)
  const size_t MB = 1ull << 20;
  char* base = (char*)d_ws;
  bf16* qx = (bf16*)(base + 0 * MB);
  bf16* kx = (bf16*)(base + 32 * MB);
  bf16* wq = (bf16*)(base + 64 * MB);
  bf16* wk = (bf16*)(base + 66 * MB);
  bf16* S = (bf16*)(base + 0 * MB);
  bf16* qp = (bf16*)(base + 128 * MB);
  bf16* kp = (bf16*)(base + 160 * MB);
  bf16* P = (bf16*)(base + 128 * MB);
  bf16* vt = (bf16*)(base + 192 * MB);

  cvt_f32_bf16<<<8192, 256, 0, stream>>>(query, qx, 2097152);
  cvt_f32_bf16<<<8192, 256, 0, stream>>>(key_in, kx, 2097152);
  cvt_f32_bf16<<<512, 256, 0, stream>>>(Wq_w, wq, 131072);
  cvt_f32_bf16<<<512, 256, 0, stream>>>(Wk_w, wk, 131072);
  transpose_v<<<dim3(32, 64, 8), dim3(32, 8), 0, stream>>>(value, vt);

  // projections: q = query @ Wq^T + b, k = key @ Wk^T + b   (bf16 out)
  gemm256<0, 0><<<dim3(4, 64, 1), 512, 0, stream>>>(
      qx, wq, qp, Wq_b, nullptr, 16384, 1024, 1024, 0, 0, 0);
  gemm256<0, 0><<<dim3(4, 64, 1), 512, 0, stream>>>(
      kx, wk, kp, Wk_b, nullptr, 16384, 1024, 1024, 0, 0, 0);
  // scores: S = mask ? (q @ k^T)/32 : -1e9   (bf16 out, batched)
  gemm256<1, 1><<<dim3(8, 8, 8), 512, 0, stream>>>(
      qp, kp, S, nullptr, mask, 2048, 2048, 1024, 2048LL * 1024,
      2048LL * 1024, 2048LL * 2048);
  softmax_rows<<<16384, 256, 0, stream>>>(S, P);
  // out = P @ V  (via V^T, f32 out, batched)
  gemm256<2, 1><<<dim3(4, 8, 8), 512, 0, stream>>>(
      P, vt, out, nullptr, nullptr, 2048, 1024, 2048, 2048LL * 2048,
      1024LL * 2048, 2048LL * 1024);
}